// Round 1
// baseline (321.326 us; speedup 1.0000x reference)
//
#include <hip/hip_runtime.h>

typedef unsigned short u16;
typedef unsigned int u32;
typedef long long i64;
typedef __bf16 bf16x8 __attribute__((ext_vector_type(8)));
typedef u16 u16x8 __attribute__((ext_vector_type(8)));
typedef float f32x4 __attribute__((ext_vector_type(4)));

#define DEV __device__ __forceinline__

// problem constants (fixed by harness)
constexpr int BB = 2, DD = 512, NN = 2048, HH = 8, DKc = 64, D2 = 1024;

// workspace byte offsets (all 16B aligned); total ~48.3 MB
constexpr i64 OFF_CAT = 0;              // bf16 [B][N][D2]  concat^T: [0:512)=merge out, [512:1024)=init_query^T
constexpr i64 OFF_XKT = 8388608;        // bf16 [B][N][D]   key_t^T
constexpr i64 OFF_XVT = 12582912;       // bf16 [B][N][D]   value^T
constexpr i64 OFF_QH  = 16777216;       // bf16 [B][H][N][DK]
constexpr i64 OFF_KH  = 20971520;       // bf16 [B][H][N][DK]
constexpr i64 OFF_VT  = 25165824;       // bf16 [B][H][DK][N]
constexpr i64 OFF_OT  = 29360128;       // bf16 [B][N][D] (c = h*64+dk)
constexpr i64 OFF_HT  = 33554432;       // bf16 [B][N][D2]
constexpr i64 OFF_WQP = 41943040;       // bf16 512x512 row-perm o'=h*64+dk
constexpr i64 OFF_WKP = 42467328;
constexpr i64 OFF_WVP = 42991616;
constexpr i64 OFF_WMP = 43515904;       // bf16 512x512 col-perm c=h*64+dk
constexpr i64 OFF_W1B = 44040192;       // bf16 1024x1024
constexpr i64 OFF_W2B = 46137344;       // bf16 512x1024
constexpr i64 OFF_BQP = 47185920;       // f32 512 (permuted)
constexpr i64 OFF_BKP = 47187968;
constexpr i64 OFF_BVP = 47190016;
constexpr i64 OFF_BNA = 47192064;       // f32 1024 BN scale
constexpr i64 OFF_BNC = 47196160;       // f32 1024 BN shift (incl b1)
constexpr i64 OFF_MSK = 47200256;       // u32 [B*N*64] bit-packed mask

DEV u16 f2bf(float f) {  // round-to-nearest-even f32->bf16
  u32 u = __float_as_uint(f);
  u = u + 0x7FFFu + ((u >> 16) & 1u);
  return (u16)(u >> 16);
}

DEV bf16x8 ldfrag(const u16* p) {  // 16B LDS fragment load (alias-safe)
  bf16x8 v;
  __builtin_memcpy(&v, __builtin_assume_aligned(p, 16), 16);
  return v;
}

DEV void cp16(const u16* __restrict__ g, u16* l) {  // global 16B -> LDS 16B
  u16x8 v = *(const u16x8*)g;
  *(u16x8*)l = v;
}

// ---------------- prep: weight convert/permute, BN fold, mask bit-pack ----------------
__global__ __launch_bounds__(256) void prep_kernel(
    const float* __restrict__ Wq, const float* __restrict__ Wk, const float* __restrict__ Wv,
    const float* __restrict__ Wm, const float* __restrict__ W1, const float* __restrict__ W2,
    const float* __restrict__ bq, const float* __restrict__ bk, const float* __restrict__ bv,
    const float* __restrict__ b1, const float* __restrict__ gamma_, const float* __restrict__ beta_,
    const float* __restrict__ rmean, const float* __restrict__ rvar, const int* __restrict__ mask,
    u16* __restrict__ wqp, u16* __restrict__ wkp, u16* __restrict__ wvp, u16* __restrict__ wmp,
    u16* __restrict__ w1b, u16* __restrict__ w2b,
    float* __restrict__ bqp, float* __restrict__ bkp, float* __restrict__ bvp,
    float* __restrict__ bna, float* __restrict__ bnc, u32* __restrict__ mw) {
  const int blk = blockIdx.x, t = threadIdx.x;
  if (blk < 768) {  // Wq/Wk/Wv row-permute: dst row o'=h*64+dk <- src row dk*8+h
    const int which = blk >> 8, lb = blk & 255;
    const float* W = which == 0 ? Wq : (which == 1 ? Wk : Wv);
    u16* dst = which == 0 ? wqp : (which == 1 ? wkp : wvp);
    for (int e = lb * 256 + t; e < 262144; e += 65536) {
      int op = e >> 9, i = e & 511;
      int dk = op & 63, h = op >> 6;
      dst[e] = f2bf(W[(dk * 8 + h) * 512 + i]);
    }
  } else if (blk < 1024) {  // Wm column-permute: dst col c=h*64+dk <- src col dk*8+h
    const int lb = blk - 768;
    for (int e = lb * 256 + t; e < 262144; e += 65536) {
      int o = e >> 9, c = e & 511;
      int dk = c & 63, h = c >> 6;
      wmp[e] = f2bf(Wm[o * 512 + dk * 8 + h]);
    }
  } else if (blk < 1536) {  // W1 straight convert
    const int lb = blk - 1024;
    for (int e = lb * 256 + t; e < 1048576; e += 131072) w1b[e] = f2bf(W1[e]);
  } else if (blk < 1792) {  // W2 straight convert
    const int lb = blk - 1536;
    for (int e = lb * 256 + t; e < 524288; e += 65536) w2b[e] = f2bf(W2[e]);
  } else if (blk == 1792) {  // vectors: permuted biases + folded BN
    for (int e = t; e < 512; e += 256) {
      int src = (e & 63) * 8 + (e >> 6);
      bqp[e] = bq[src]; bkp[e] = bk[src]; bvp[e] = bv[src];
    }
    for (int e = t; e < 1024; e += 256) {
      float a = gamma_[e] * rsqrtf(rvar[e] + 1e-5f);
      bna[e] = a;
      bnc[e] = (b1[e] - rmean[e]) * a + beta_[e];
    }
  } else {  // mask bit-pack via ballot: 64 ints/wave-iter -> 2 words
    const int wid = (blk - 1793) * 4 + (t >> 6), lane = t & 63;
    for (i64 base = (i64)wid * 64; base < (i64)BB * NN * NN; base += (i64)4096 * 64) {
      int v = mask[base + lane];
      unsigned long long bits = __ballot(v != 0);
      if (lane == 0) mw[base >> 5] = (u32)bits;
      else if (lane == 1) mw[(base >> 5) + 1] = (u32)(bits >> 32);
    }
  }
}

// ---------------- transpose+convert: (B,D,N) f32 -> (B,N,D) bf16 ----------------
__global__ __launch_bounds__(256) void transpose_cvt(const float* __restrict__ iq,
                                                     const float* __restrict__ kt,
                                                     const float* __restrict__ vv,
                                                     u16* __restrict__ cat, u16* __restrict__ xkt,
                                                     u16* __restrict__ xvt) {
  __shared__ float tile[32][33];
  const int z = blockIdx.z, tensor = z >> 1, b = z & 1;
  const float* src = tensor == 0 ? iq : (tensor == 1 ? kt : vv);
  src += (i64)b * DD * NN;
  u16* dst; i64 ldd; int coff;
  if (tensor == 0)      { dst = cat + (i64)b * NN * D2; ldd = D2; coff = DD; }
  else if (tensor == 1) { dst = xkt + (i64)b * NN * DD; ldd = DD; coff = 0; }
  else                  { dst = xvt + (i64)b * NN * DD; ldd = DD; coff = 0; }
  const int x0 = blockIdx.x * 32, y0 = blockIdx.y * 32;
  const int col = threadIdx.x & 31, rg = threadIdx.x >> 5;
#pragma unroll
  for (int i = 0; i < 4; ++i) {
    int row = rg + i * 8;
    tile[row][col] = src[(i64)(y0 + row) * NN + x0 + col];
  }
  __syncthreads();
#pragma unroll
  for (int i = 0; i < 4; ++i) {
    int rr = rg + i * 8;
    dst[(i64)(x0 + rr) * ldd + coff + y0 + col] = f2bf(tile[col][rr]);
  }
}

// ---------------- generic gemm_bt: C[m][n] = A[m][:]·B[n][:] (+epilogue) ----------------
// 128x128 tile, BK=64, 4 waves in 2x2, 16x16x32 bf16 MFMA, pitch-72 LDS (conflict-free-ish)
struct GArgs {
  const u16* A; i64 lda, sAb;
  const u16* B; i64 ldb, sBb;
  void* C; i64 ldc, sCb;
  const float* p1; const float* p2;
  int K;
};

template <int MODE>
__global__ __launch_bounds__(256) void gemm_bt(GArgs g) {
  __shared__ __align__(16) u16 As[128 * 72];
  __shared__ __align__(16) u16 Bs[128 * 72];
  const int t = threadIdx.x;
  const int w = t >> 6, l = t & 63, quad = l >> 4, l15 = l & 15;
  const int wm = (w >> 1) * 64, wn = (w & 1) * 64;
  const int bz = blockIdx.z;
  const u16* A = g.A + (i64)bz * g.sAb + (i64)blockIdx.x * 128 * g.lda;
  const u16* Bp = g.B + (i64)bz * g.sBb + (i64)blockIdx.y * 128 * g.ldb;
  f32x4 acc[4][4] = {};
  for (int kk = 0; kk < g.K; kk += 64) {
    __syncthreads();
#pragma unroll
    for (int it = 0; it < 4; ++it) {
      int gi = it * 256 + t, r = gi >> 3, c = gi & 7;
      cp16(A + (i64)r * g.lda + kk + c * 8, &As[r * 72 + c * 8]);
      cp16(Bp + (i64)r * g.ldb + kk + c * 8, &Bs[r * 72 + c * 8]);
    }
    __syncthreads();
#pragma unroll
    for (int kc = 0; kc < 2; ++kc) {
      bf16x8 af[4], bfr[4];
#pragma unroll
      for (int i = 0; i < 4; ++i) {
        af[i]  = ldfrag(&As[(wm + i * 16 + l15) * 72 + kc * 32 + quad * 8]);
        bfr[i] = ldfrag(&Bs[(wn + i * 16 + l15) * 72 + kc * 32 + quad * 8]);
      }
#pragma unroll
      for (int i = 0; i < 4; ++i)
#pragma unroll
        for (int j = 0; j < 4; ++j)
          acc[i][j] = __builtin_amdgcn_mfma_f32_16x16x32_bf16(af[i], bfr[j], acc[i][j], 0, 0, 0);
    }
  }
  // epilogue: C/D layout col=lane&15, row=quad*4+reg (m89-verified)
  const int rowBase = blockIdx.x * 128 + wm + quad * 4;
  const int colBase = blockIdx.y * 128 + wn + l15;
#pragma unroll
  for (int j = 0; j < 4; ++j) {
    const int col = colBase + j * 16;
    float cA = 0.f, cB = 0.f;
    if (MODE == 0 || MODE == 1) cA = g.p1[col];
    if (MODE == 3) { cA = g.p1[col]; cB = g.p2[col]; }
#pragma unroll
    for (int i = 0; i < 4; ++i) {
#pragma unroll
      for (int r = 0; r < 4; ++r) {
        const int row = rowBase + i * 16 + r;
        float v = acc[i][j][r];
        if (MODE == 0) {  // bf16 plain store, col bias (merge -> catT)
          ((u16*)g.C + (i64)bz * g.sCb)[(i64)row * g.ldc + col] = f2bf(v + cA);
        } else if (MODE == 1) {  // Q/K head scatter: col=o'=h*64+dk -> [h][n][dk]
          ((u16*)g.C + (i64)bz * g.sCb)[(i64)(col >> 6) * (NN * 64) + (i64)row * 64 + (col & 63)] =
              f2bf(v + cA);
        } else if (MODE == 2) {  // bf16 plain store, row bias (V-proj -> Vt)
          ((u16*)g.C + (i64)bz * g.sCb)[(i64)row * g.ldc + col] = f2bf(v + g.p1[row]);
        } else if (MODE == 3) {  // BN+ReLU (scale/shift per col, b1 folded)
          float x = v * cA + cB;
          ((u16*)g.C + (i64)bz * g.sCb)[(i64)row * g.ldc + col] = f2bf(x > 0.f ? x : 0.f);
        } else {  // MODE 4: fp32 out, row bias (W2 -> d_out)
          ((float*)g.C + (i64)bz * g.sCb)[(i64)row * g.ldc + col] = v + g.p1[row];
        }
      }
    }
  }
}

// ---------------- flash attention: per (b,h,64-row q-tile), online softmax ----------------
__global__ __launch_bounds__(256) void flash_attn(const u16* __restrict__ Qh, const u16* __restrict__ Kh,
                                                  const u16* __restrict__ Vt, const u32* __restrict__ MW,
                                                  u16* __restrict__ Ot) {
  __shared__ __align__(16) u16 Qs[64 * 72];
  __shared__ __align__(16) u16 Ks[64 * 72];
  __shared__ __align__(16) u16 Vs[64 * 72];
  __shared__ __align__(16) u16 Ps[4][16 * 72];
  const int t = threadIdx.x, w = t >> 6, l = t & 63, quad = l >> 4, l15 = l & 15;
  const int nt = blockIdx.x, h = blockIdx.y, b = blockIdx.z;
  const u16* Qb = Qh + ((i64)(b * HH + h) * NN + nt * 64) * DKc;
  const u16* Kb = Kh + (i64)(b * HH + h) * NN * DKc;
  const u16* Vb = Vt + (i64)(b * HH + h) * DKc * NN;
#pragma unroll
  for (int it = 0; it < 2; ++it) {
    int gi = it * 256 + t, r = gi >> 3, c = gi & 7;
    cp16(Qb + r * 64 + c * 8, &Qs[r * 72 + c * 8]);
  }
  __syncthreads();
  bf16x8 qf[2];  // wave's 16 q-rows, full DK=64 in 2 k-chunks, kept in regs
#pragma unroll
  for (int kc = 0; kc < 2; ++kc) qf[kc] = ldfrag(&Qs[(w * 16 + l15) * 72 + kc * 32 + quad * 8]);

  f32x4 oacc[4] = {};
  float mrun[4], lrun[4];
#pragma unroll
  for (int r = 0; r < 4; ++r) { mrun[r] = -__builtin_inff(); lrun[r] = 0.f; }

  for (int mt = 0; mt < NN / 64; ++mt) {
    __syncthreads();
#pragma unroll
    for (int it = 0; it < 2; ++it) {
      int gi = it * 256 + t, r = gi >> 3, c = gi & 7;
      cp16(Kb + (i64)(mt * 64 + r) * 64 + c * 8, &Ks[r * 72 + c * 8]);
      cp16(Vb + (i64)r * NN + mt * 64 + c * 8, &Vs[r * 72 + c * 8]);
    }
    __syncthreads();
    // S = Q K^T  (16 rows x 64 cols per wave)
    f32x4 s[4];
#pragma unroll
    for (int ct = 0; ct < 4; ++ct) {
      bf16x8 k0 = ldfrag(&Ks[(ct * 16 + l15) * 72 + quad * 8]);
      bf16x8 k1 = ldfrag(&Ks[(ct * 16 + l15) * 72 + 32 + quad * 8]);
      f32x4 z = {};
      z = __builtin_amdgcn_mfma_f32_16x16x32_bf16(qf[0], k0, z, 0, 0, 0);
      z = __builtin_amdgcn_mfma_f32_16x16x32_bf16(qf[1], k1, z, 0, 0, 0);
      s[ct] = z;
    }
    // mask words: 64 cols of this m-tile = 2 words per q-row
    u32 mw0[4], mw1[4];
#pragma unroll
    for (int r = 0; r < 4; ++r) {
      int n = nt * 64 + w * 16 + quad * 4 + r;
      i64 base = ((i64)b * NN + n) * 64 + mt * 2;
      mw0[r] = MW[base]; mw1[r] = MW[base + 1];
    }
    float mloc[4];
#pragma unroll
    for (int r = 0; r < 4; ++r) mloc[r] = -__builtin_inff();
#pragma unroll
    for (int ct = 0; ct < 4; ++ct)
#pragma unroll
      for (int r = 0; r < 4; ++r) {
        float sv = s[ct][r] * 0.125f;  // 1/sqrt(64)
        u32 mword = (ct < 2) ? mw0[r] : mw1[r];
        int bit = ((ct & 1) << 4) + l15;
        sv = ((mword >> bit) & 1u) ? sv : -1e9f;  // exact reference where() semantics
        s[ct][r] = sv;
        mloc[r] = fmaxf(mloc[r], sv);
      }
#pragma unroll
    for (int off = 1; off < 16; off <<= 1)
#pragma unroll
      for (int r = 0; r < 4; ++r) mloc[r] = fmaxf(mloc[r], __shfl_xor(mloc[r], off));
    float alpha[4];
#pragma unroll
    for (int r = 0; r < 4; ++r) {
      float mn = fmaxf(mrun[r], mloc[r]);
      alpha[r] = __expf(mrun[r] - mn);
      mrun[r] = mn;
    }
    float ls[4] = {0.f, 0.f, 0.f, 0.f};
#pragma unroll
    for (int ct = 0; ct < 4; ++ct)
#pragma unroll
      for (int r = 0; r < 4; ++r) {
        float p = __expf(s[ct][r] - mrun[r]);
        s[ct][r] = p;
        ls[r] += p;
      }
#pragma unroll
    for (int off = 1; off < 16; off <<= 1)
#pragma unroll
      for (int r = 0; r < 4; ++r) ls[r] += __shfl_xor(ls[r], off);
#pragma unroll
    for (int r = 0; r < 4; ++r) lrun[r] = lrun[r] * alpha[r] + ls[r];
    // P -> LDS (C-layout -> A-operand layout round trip; per-wave private)
#pragma unroll
    for (int ct = 0; ct < 4; ++ct)
#pragma unroll
      for (int r = 0; r < 4; ++r)
        Ps[w][(quad * 4 + r) * 72 + ct * 16 + l15] = f2bf(s[ct][r]);
    asm volatile("" ::: "memory");
#pragma unroll
    for (int dt = 0; dt < 4; ++dt)
#pragma unroll
      for (int r = 0; r < 4; ++r) oacc[dt][r] *= alpha[r];
    bf16x8 pf[2];
#pragma unroll
    for (int kc = 0; kc < 2; ++kc) pf[kc] = ldfrag(&Ps[w][l15 * 72 + kc * 32 + quad * 8]);
#pragma unroll
    for (int dt = 0; dt < 4; ++dt) {
      bf16x8 v0 = ldfrag(&Vs[(dt * 16 + l15) * 72 + quad * 8]);
      bf16x8 v1 = ldfrag(&Vs[(dt * 16 + l15) * 72 + 32 + quad * 8]);
      oacc[dt] = __builtin_amdgcn_mfma_f32_16x16x32_bf16(pf[0], v0, oacc[dt], 0, 0, 0);
      oacc[dt] = __builtin_amdgcn_mfma_f32_16x16x32_bf16(pf[1], v1, oacc[dt], 0, 0, 0);
    }
  }
  // epilogue: O[n][dk] -> Ot[b][n][h*64+dk] (coalesced)
#pragma unroll
  for (int dt = 0; dt < 4; ++dt)
#pragma unroll
    for (int r = 0; r < 4; ++r) {
      int n = nt * 64 + w * 16 + quad * 4 + r;
      float v = oacc[dt][r] / lrun[r];
      Ot[((i64)b * NN + n) * DD + h * DKc + dt * 16 + l15] = f2bf(v);
    }
}

extern "C" void kernel_launch(void* const* d_in, const int* in_sizes, int n_in,
                              void* d_out, int out_size, void* d_ws, size_t ws_size,
                              hipStream_t stream) {
  (void)in_sizes; (void)n_in; (void)out_size; (void)ws_size;
  const float* iq    = (const float*)d_in[0];
  const float* kt    = (const float*)d_in[1];
  const float* vv    = (const float*)d_in[2];
  const int*   mask  = (const int*)d_in[3];
  const float* Wq    = (const float*)d_in[4];
  const float* bq    = (const float*)d_in[5];
  const float* Wk    = (const float*)d_in[6];
  const float* bk    = (const float*)d_in[7];
  const float* Wv    = (const float*)d_in[8];
  const float* bv    = (const float*)d_in[9];
  const float* Wm    = (const float*)d_in[10];
  const float* bm    = (const float*)d_in[11];
  const float* W1    = (const float*)d_in[12];
  const float* b1    = (const float*)d_in[13];
  const float* gamma_= (const float*)d_in[14];
  const float* beta_ = (const float*)d_in[15];
  const float* rmean = (const float*)d_in[16];
  const float* rvar  = (const float*)d_in[17];
  const float* W2    = (const float*)d_in[18];
  const float* b2    = (const float*)d_in[19];

  char* ws = (char*)d_ws;
  u16* cat = (u16*)(ws + OFF_CAT);
  u16* xkt = (u16*)(ws + OFF_XKT);
  u16* xvt = (u16*)(ws + OFF_XVT);
  u16* qh  = (u16*)(ws + OFF_QH);
  u16* kh  = (u16*)(ws + OFF_KH);
  u16* vt  = (u16*)(ws + OFF_VT);
  u16* ot  = (u16*)(ws + OFF_OT);
  u16* ht  = (u16*)(ws + OFF_HT);
  u16* wqp = (u16*)(ws + OFF_WQP);
  u16* wkp = (u16*)(ws + OFF_WKP);
  u16* wvp = (u16*)(ws + OFF_WVP);
  u16* wmp = (u16*)(ws + OFF_WMP);
  u16* w1b = (u16*)(ws + OFF_W1B);
  u16* w2b = (u16*)(ws + OFF_W2B);
  float* bqp = (float*)(ws + OFF_BQP);
  float* bkp = (float*)(ws + OFF_BKP);
  float* bvp = (float*)(ws + OFF_BVP);
  float* bna = (float*)(ws + OFF_BNA);
  float* bnc = (float*)(ws + OFF_BNC);
  u32* mw = (u32*)(ws + OFF_MSK);

  prep_kernel<<<2817, 256, 0, stream>>>(Wq, Wk, Wv, Wm, W1, W2, bq, bk, bv, b1, gamma_, beta_,
                                        rmean, rvar, mask, wqp, wkp, wvp, wmp, w1b, w2b,
                                        bqp, bkp, bvp, bna, bnc, mw);
  transpose_cvt<<<dim3(64, 16, 6), 256, 0, stream>>>(iq, kt, vv, cat, xkt, xvt);

  // Q proj: C[n][o'] = iq^T · Wq_p^T  -> Qh[b][h][n][dk]
  GArgs qa{cat + DD, D2, (i64)NN * D2, wqp, DD, 0, qh, 0, (i64)HH * NN * DKc, bqp, nullptr, DD};
  gemm_bt<1><<<dim3(16, 4, 2), 256, 0, stream>>>(qa);
  // K proj
  GArgs ka{xkt, DD, (i64)NN * DD, wkp, DD, 0, kh, 0, (i64)HH * NN * DKc, bkp, nullptr, DD};
  gemm_bt<1><<<dim3(16, 4, 2), 256, 0, stream>>>(ka);
  // V proj: C[o'][m] = Wv_p · value^T^T -> Vt[b][h][dk][m]
  GArgs va{wvp, DD, 0, xvt, DD, (i64)NN * DD, vt, NN, (i64)HH * DKc * NN, bvp, nullptr, DD};
  gemm_bt<2><<<dim3(4, 16, 2), 256, 0, stream>>>(va);

  flash_attn<<<dim3(32, 8, 2), 256, 0, stream>>>(qh, kh, vt, mw, ot);

  // merge: C[n][o] = Ot · Wm_p^T -> catT[:, 0:512]
  GArgs ma{ot, DD, (i64)NN * DD, wmp, DD, 0, cat, D2, (i64)NN * D2, bm, nullptr, DD};
  gemm_bt<0><<<dim3(16, 4, 2), 256, 0, stream>>>(ma);
  // W1 + BN + ReLU: C[n][e] -> hT
  GArgs wa{cat, D2, (i64)NN * D2, w1b, D2, 0, ht, D2, (i64)NN * D2, bna, bnc, D2};
  gemm_bt<3><<<dim3(16, 8, 2), 256, 0, stream>>>(wa);
  // W2: C[o][n] -> d_out (fp32)
  GArgs w2a{w2b, D2, 0, ht, D2, (i64)NN * D2, d_out, NN, (i64)DD * NN, b2, nullptr, D2};
  gemm_bt<4><<<dim3(4, 16, 2), 256, 0, stream>>>(w2a);
}

// Round 2
// 261.966 us; speedup vs baseline: 1.2266x; 1.2266x over previous
//
#include <hip/hip_runtime.h>

typedef unsigned short u16;
typedef unsigned int u32;
typedef unsigned long long u64;
typedef long long i64;
typedef __bf16 bf16x8 __attribute__((ext_vector_type(8)));
typedef float f32x4 __attribute__((ext_vector_type(4)));

#define DEV __device__ __forceinline__

// problem constants (fixed by harness)
constexpr int BB = 2, DD = 512, NN = 2048, HH = 8, DKc = 64, D2 = 1024;

// Q pre-scale: 1/sqrt(64) * log2(e)  (folded into Q so softmax uses native exp2)
constexpr float QSC = 0.125f * 1.44269504088896340736f;

// workspace byte offsets (16B aligned)
constexpr i64 OFF_CAT = 0;              // bf16 [B][N][D2] concatT; [512:1024)=init_query^T
constexpr i64 OFF_XKT = 8388608;        // bf16 [B][N][D] key_t^T   (dead after K-proj)
constexpr i64 OFF_XVT = 12582912;       // bf16 [B][N][D] value^T   (dead after V-proj)
constexpr i64 OFF_OP0 = 8388608;        // f32 [B][H][N][DK] flash partial s=0 (reuses XKT+XVT)
constexpr i64 OFF_QH  = 16777216;       // bf16 [B][H][N][DK]
constexpr i64 OFF_KH  = 20971520;       // bf16 [B][H][N][DK]
constexpr i64 OFF_VT  = 25165824;       // bf16 [B][H][DK][N]
constexpr i64 OFF_OT  = 29360128;       // bf16 [B][N][D]
constexpr i64 OFF_HT  = 33554432;       // bf16 [B][N][D2]
constexpr i64 OFF_OP1 = 33554432;       // f32 partial s=1 (reuses HT; HT written after combine)
constexpr i64 OFF_WQP = 41943040;       // bf16 512x512 row-perm o'=h*64+dk
constexpr i64 OFF_WKP = 42467328;
constexpr i64 OFF_WVP = 42991616;
constexpr i64 OFF_WMP = 43515904;       // bf16 512x512 col-perm
constexpr i64 OFF_W1B = 44040192;       // bf16 1024x1024
constexpr i64 OFF_W2B = 46137344;       // bf16 512x1024
constexpr i64 OFF_BQP = 47185920;       // f32 512 (permuted)
constexpr i64 OFF_BKP = 47187968;
constexpr i64 OFF_BVP = 47190016;
constexpr i64 OFF_BNA = 47192064;       // f32 1024 BN scale
constexpr i64 OFF_BNC = 47196160;       // f32 1024 BN shift (incl b1)
constexpr i64 OFF_MSK = 47200256;       // bit-packed mask, 1 MB
constexpr i64 OFF_LP  = 48248832;       // f32 [S=2][B][H][N] flash partial row-sums

DEV u16 f2bf(float f) {  // round-to-nearest-even f32->bf16
  u32 u = __float_as_uint(f);
  u = u + 0x7FFFu + ((u >> 16) & 1u);
  return (u16)(u >> 16);
}

DEV float bf2f(u16 u) { return __uint_as_float(((u32)u) << 16); }

DEV bf16x8 ldfrag(const u16* p) {  // 16B-aligned LDS fragment load
  bf16x8 v;
  __builtin_memcpy(&v, __builtin_assume_aligned(p, 16), 16);
  return v;
}

DEV bf16x8 ldfrag8(const u16* p) {  // 8B-aligned 16B LDS fragment load (2x b64)
  bf16x8 v;
  __builtin_memcpy(&v, __builtin_assume_aligned(p, 8), 16);
  return v;
}

// async global->LDS, 16B per lane; LDS dest = wave-uniform base + lane*16
DEV void gload16(const void* g, void* lds) {
  __builtin_amdgcn_global_load_lds((__attribute__((address_space(1))) void*)g,
                                   (__attribute__((address_space(3))) void*)lds, 16, 0, 0);
}

DEV f32x4 mfma16(bf16x8 a, bf16x8 b, f32x4 c) {
  return __builtin_amdgcn_mfma_f32_16x16x32_bf16(a, b, c, 0, 0, 0);
}

// ---------------- prep: weight convert/permute, BN fold, mask bit-pack ----------------
__global__ __launch_bounds__(256) void prep_kernel(
    const float* __restrict__ Wq, const float* __restrict__ Wk, const float* __restrict__ Wv,
    const float* __restrict__ Wm, const float* __restrict__ W1, const float* __restrict__ W2,
    const float* __restrict__ bq, const float* __restrict__ bk, const float* __restrict__ bv,
    const float* __restrict__ b1, const float* __restrict__ gamma_, const float* __restrict__ beta_,
    const float* __restrict__ rmean, const float* __restrict__ rvar, const int* __restrict__ mask,
    u16* __restrict__ wqp, u16* __restrict__ wkp, u16* __restrict__ wvp, u16* __restrict__ wmp,
    u16* __restrict__ w1b, u16* __restrict__ w2b,
    float* __restrict__ bqp, float* __restrict__ bkp, float* __restrict__ bvp,
    float* __restrict__ bna, float* __restrict__ bnc, u32* __restrict__ mw) {
  const int blk = blockIdx.x, t = threadIdx.x;
  if (blk < 768) {  // Wq/Wk/Wv row-permute: dst row o'=h*64+dk <- src row dk*8+h
    const int which = blk >> 8, lb = blk & 255;
    const float* W = which == 0 ? Wq : (which == 1 ? Wk : Wv);
    u16* dst = which == 0 ? wqp : (which == 1 ? wkp : wvp);
    for (int e = lb * 256 + t; e < 262144; e += 65536) {
      int op = e >> 9, i = e & 511;
      int dk = op & 63, h = op >> 6;
      dst[e] = f2bf(W[(dk * 8 + h) * 512 + i]);
    }
  } else if (blk < 1024) {  // Wm column-permute
    const int lb = blk - 768;
    for (int e = lb * 256 + t; e < 262144; e += 65536) {
      int o = e >> 9, c = e & 511;
      int dk = c & 63, h = c >> 6;
      wmp[e] = f2bf(Wm[o * 512 + dk * 8 + h]);
    }
  } else if (blk < 1536) {  // W1 convert
    const int lb = blk - 1024;
    for (int e = lb * 256 + t; e < 1048576; e += 131072) w1b[e] = f2bf(W1[e]);
  } else if (blk < 1792) {  // W2 convert
    const int lb = blk - 1536;
    for (int e = lb * 256 + t; e < 524288; e += 65536) w2b[e] = f2bf(W2[e]);
  } else if (blk == 1792) {  // vectors: permuted biases + folded BN
    for (int e = t; e < 512; e += 256) {
      int src = (e & 63) * 8 + (e >> 6);
      bqp[e] = bq[src]; bkp[e] = bk[src]; bvp[e] = bv[src];
    }
    for (int e = t; e < 1024; e += 256) {
      float a = gamma_[e] * rsqrtf(rvar[e] + 1e-5f);
      bna[e] = a;
      bnc[e] = (b1[e] - rmean[e]) * a + beta_[e];
    }
  } else {  // mask pack: each lane packs its own 32 consecutive ints -> one u32
    const int tid = (blk - 1793) * 256 + t;  // [0, 262144)
    const i64 base = (i64)tid * 32;
    const int4* mp = (const int4*)(mask + base);
    u32 word = 0;
#pragma unroll
    for (int j = 0; j < 8; ++j) {
      int4 x = mp[j];
      u32 nib = (x.x != 0 ? 1u : 0u) | (x.y != 0 ? 2u : 0u) | (x.z != 0 ? 4u : 0u) |
                (x.w != 0 ? 8u : 0u);
      word |= nib << (j * 4);
    }
    mw[tid] = word;
  }
}

// ---------------- transpose+convert: (B,D,N) f32 -> (B,N,D) bf16 ----------------
__global__ __launch_bounds__(256) void transpose_cvt(const float* __restrict__ iq,
                                                     const float* __restrict__ kt,
                                                     const float* __restrict__ vv,
                                                     u16* __restrict__ cat, u16* __restrict__ xkt,
                                                     u16* __restrict__ xvt) {
  __shared__ float tile[32][33];
  const int z = blockIdx.z, tensor = z >> 1, b = z & 1;
  const float* src = tensor == 0 ? iq : (tensor == 1 ? kt : vv);
  src += (i64)b * DD * NN;
  u16* dst; i64 ldd; int coff;
  if (tensor == 0)      { dst = cat + (i64)b * NN * D2; ldd = D2; coff = DD; }
  else if (tensor == 1) { dst = xkt + (i64)b * NN * DD; ldd = DD; coff = 0; }
  else                  { dst = xvt + (i64)b * NN * DD; ldd = DD; coff = 0; }
  const int x0 = blockIdx.x * 32, y0 = blockIdx.y * 32;
  const int col = threadIdx.x & 31, rg = threadIdx.x >> 5;
#pragma unroll
  for (int i = 0; i < 4; ++i) {
    int row = rg + i * 8;
    tile[row][col] = src[(i64)(y0 + row) * NN + x0 + col];
  }
  __syncthreads();
#pragma unroll
  for (int i = 0; i < 4; ++i) {
    int rr = rg + i * 8;
    dst[(i64)(x0 + rr) * ldd + coff + y0 + col] = f2bf(tile[col][rr]);
  }
}

// ---------------- gemm_bt: C[m][n] = A[m][:]·B[n][:] (+epilogue) ----------------
// 128x64 tile, BK=64, 4 waves 2x2 over (64x32), global_load_lds staging with
// XOR-8 chunk swizzle on the GLOBAL side => pitch-64 LDS, conflict-free frag reads.
struct GArgs {
  const u16* A; i64 lda, sAb;
  const u16* B; i64 ldb, sBb;
  void* C; i64 ldc, sCb;
  const float* p1; const float* p2;
  int K; float sc;
};

template <int MODE>
__global__ __launch_bounds__(256) void gemm_bt(GArgs g) {
  __shared__ __align__(16) u16 As[128 * 64];
  __shared__ __align__(16) u16 Bs[64 * 64];
  const int t = threadIdx.x;
  const int w = t >> 6, l = t & 63, quad = l >> 4, l15 = l & 15;
  const int wm = (w >> 1) * 64, wn = (w & 1) * 32;
  const int bz = blockIdx.z;
  const u16* A = g.A + (i64)bz * g.sAb + (i64)blockIdx.x * 128 * g.lda;
  const u16* Bp = g.B + (i64)bz * g.sBb + (i64)blockIdx.y * 64 * g.ldb;
  f32x4 acc[4][2] = {};
  for (int kk = 0; kk < g.K; kk += 64) {
    __syncthreads();
#pragma unroll
    for (int j = 0; j < 4; ++j) {  // A: 128 rows x 8 chunks = 1024 chunks
      int ch = j * 256 + w * 64 + l, r = ch >> 3, c = ch & 7;
      gload16(A + (i64)r * g.lda + kk + ((c ^ (r & 7)) << 3), &As[(j * 256 + w * 64) * 8]);
    }
#pragma unroll
    for (int j = 0; j < 2; ++j) {  // B: 64 rows x 8 chunks = 512 chunks
      int ch = j * 256 + w * 64 + l, r = ch >> 3, c = ch & 7;
      gload16(Bp + (i64)r * g.ldb + kk + ((c ^ (r & 7)) << 3), &Bs[(j * 256 + w * 64) * 8]);
    }
    __syncthreads();
#pragma unroll
    for (int kc = 0; kc < 2; ++kc) {
      const int sw = ((kc * 4 + quad) ^ (l15 & 7)) << 3;
      bf16x8 af[4], bfr[2];
#pragma unroll
      for (int i = 0; i < 4; ++i) af[i] = ldfrag(&As[(wm + i * 16 + l15) * 64 + sw]);
#pragma unroll
      for (int j = 0; j < 2; ++j) bfr[j] = ldfrag(&Bs[(wn + j * 16 + l15) * 64 + sw]);
#pragma unroll
      for (int i = 0; i < 4; ++i)
#pragma unroll
        for (int j = 0; j < 2; ++j) acc[i][j] = mfma16(af[i], bfr[j], acc[i][j]);
    }
  }
  // epilogue: C/D layout col=lane&15, row=quad*4+reg (m89-verified)
  const int rowBase = blockIdx.x * 128 + wm + quad * 4;
  const int colBase = blockIdx.y * 64 + wn + l15;
#pragma unroll
  for (int j = 0; j < 2; ++j) {
    const int col = colBase + j * 16;
    float cA = 0.f, cB = 0.f;
    if (MODE == 0 || MODE == 1) cA = g.p1[col];
    if (MODE == 3) { cA = g.p1[col]; cB = g.p2[col]; }
#pragma unroll
    for (int i = 0; i < 4; ++i) {
#pragma unroll
      for (int r = 0; r < 4; ++r) {
        const int row = rowBase + i * 16 + r;
        float v = acc[i][j][r];
        if (MODE == 0) {  // bf16, col bias (merge -> catT)
          ((u16*)g.C + (i64)bz * g.sCb)[(i64)row * g.ldc + col] = f2bf(v + cA);
        } else if (MODE == 1) {  // Q/K head scatter + scale: col=h*64+dk -> [h][n][dk]
          ((u16*)g.C + (i64)bz * g.sCb)[(i64)(col >> 6) * (NN * 64) + (i64)row * 64 + (col & 63)] =
              f2bf((v + cA) * g.sc);
        } else if (MODE == 2) {  // bf16, row bias (V-proj -> Vt)
          ((u16*)g.C + (i64)bz * g.sCb)[(i64)row * g.ldc + col] = f2bf(v + g.p1[row]);
        } else if (MODE == 3) {  // BN+ReLU
          float x = v * cA + cB;
          ((u16*)g.C + (i64)bz * g.sCb)[(i64)row * g.ldc + col] = f2bf(x > 0.f ? x : 0.f);
        } else {  // MODE 4: fp32 out, row bias (W2 -> d_out)
          ((float*)g.C + (i64)bz * g.sCb)[(i64)row * g.ldc + col] = v + g.p1[row];
        }
      }
    }
  }
}

// ---------------- flash attention, KV-split 2, no online-softmax max ----------------
// Q pre-scaled by QSC; p = exp2(s'); masked -> 0 (== exp(-1e9-m) underflow in ref).
__global__ __launch_bounds__(256) void flash_attn(const u16* __restrict__ Qh,
                                                  const u16* __restrict__ Kh,
                                                  const u16* __restrict__ Vt,
                                                  const u64* __restrict__ MW,
                                                  float* __restrict__ Op0, float* __restrict__ Op1,
                                                  float* __restrict__ Lp) {
  __shared__ __align__(16) u16 Qs[64 * 64];
  __shared__ __align__(16) u16 Ks[64 * 64];
  __shared__ __align__(16) u16 Vs[64 * 64];
  __shared__ __align__(16) u16 Ps[4][16 * 68];  // pitch 68: store conflict-free
  const int t = threadIdx.x, w = t >> 6, l = t & 63, quad = l >> 4, l15 = l & 15;
  const int nt = blockIdx.x, h = blockIdx.y, zz = blockIdx.z, b = zz >> 1, sp = zz & 1;
  const u16* Qb = Qh + ((i64)(b * HH + h) * NN + nt * 64) * 64;
  const u16* Kb = Kh + (i64)(b * HH + h) * NN * 64;
  const u16* Vb = Vt + (i64)(b * HH + h) * 64 * NN;
#pragma unroll
  for (int j = 0; j < 2; ++j) {  // stage Q (swizzled)
    int ch = j * 256 + w * 64 + l, r = ch >> 3, c = ch & 7;
    gload16(Qb + r * 64 + ((c ^ (r & 7)) << 3), &Qs[(j * 256 + w * 64) * 8]);
  }
  __syncthreads();
  bf16x8 qf[2];
#pragma unroll
  for (int kc = 0; kc < 2; ++kc)
    qf[kc] = ldfrag(&Qs[(w * 16 + l15) * 64 + (((kc * 4 + quad) ^ (l15 & 7)) << 3)]);

  f32x4 oacc[4] = {};
  float lacc[4] = {0.f, 0.f, 0.f, 0.f};
  const int mt0 = sp * 16, mt1 = mt0 + 16;
  for (int mt = mt0; mt < mt1; ++mt) {
    __syncthreads();
#pragma unroll
    for (int j = 0; j < 2; ++j) {  // stage K,V (swizzled)
      int ch = j * 256 + w * 64 + l, r = ch >> 3, c = ch & 7;
      gload16(Kb + (i64)mt * 4096 + r * 64 + ((c ^ (r & 7)) << 3), &Ks[(j * 256 + w * 64) * 8]);
      gload16(Vb + (i64)r * NN + mt * 64 + ((c ^ (r & 7)) << 3), &Vs[(j * 256 + w * 64) * 8]);
    }
    __syncthreads();
    // S' = (Q*QSC) K^T : 16 rows x 64 cols per wave
    f32x4 s[4];
#pragma unroll
    for (int ct = 0; ct < 4; ++ct) {
      const int sw = l15 & 7;
      bf16x8 k0 = ldfrag(&Ks[(ct * 16 + l15) * 64 + ((quad ^ sw) << 3)]);
      bf16x8 k1 = ldfrag(&Ks[(ct * 16 + l15) * 64 + (((4 + quad) ^ sw) << 3)]);
      f32x4 z = {};
      z = mfma16(qf[0], k0, z);
      z = mfma16(qf[1], k1, z);
      s[ct] = z;
    }
    u64 mrow[4];
#pragma unroll
    for (int r = 0; r < 4; ++r) {
      int n = nt * 64 + w * 16 + quad * 4 + r;
      mrow[r] = MW[(i64)(b * NN + n) * 32 + mt];
    }
#pragma unroll
    for (int ct = 0; ct < 4; ++ct)
#pragma unroll
      for (int r = 0; r < 4; ++r) {
        float p = ((mrow[r] >> (ct * 16 + l15)) & 1ull) ? exp2f(s[ct][r]) : 0.f;
        lacc[r] += p;
        Ps[w][(quad * 4 + r) * 68 + ct * 16 + l15] = f2bf(p);
      }
    asm volatile("" ::: "memory");
    bf16x8 pf0 = ldfrag8(&Ps[w][l15 * 68 + quad * 8]);
    bf16x8 pf1 = ldfrag8(&Ps[w][l15 * 68 + 32 + quad * 8]);
#pragma unroll
    for (int dt = 0; dt < 4; ++dt) {
      const int sw = l15 & 7;
      bf16x8 v0 = ldfrag(&Vs[(dt * 16 + l15) * 64 + ((quad ^ sw) << 3)]);
      bf16x8 v1 = ldfrag(&Vs[(dt * 16 + l15) * 64 + (((4 + quad) ^ sw) << 3)]);
      oacc[dt] = mfma16(pf0, v0, oacc[dt]);
      oacc[dt] = mfma16(pf1, v1, oacc[dt]);
    }
  }
  // single end-of-kernel row-sum reduction across the 16 lanes of each quad-group
#pragma unroll
  for (int off = 1; off < 16; off <<= 1)
#pragma unroll
    for (int r = 0; r < 4; ++r) lacc[r] += __shfl_xor(lacc[r], off);
  float* Op = sp ? Op1 : Op0;
#pragma unroll
  for (int dt = 0; dt < 4; ++dt)
#pragma unroll
    for (int r = 0; r < 4; ++r) {
      int n = nt * 64 + w * 16 + quad * 4 + r;
      Op[((i64)(b * HH + h) * NN + n) * 64 + dt * 16 + l15] = oacc[dt][r];
    }
  if (l15 == 0) {
#pragma unroll
    for (int r = 0; r < 4; ++r) {
      int n = nt * 64 + w * 16 + quad * 4 + r;
      Lp[(i64)sp * BB * HH * NN + (i64)(b * HH + h) * NN + n] = lacc[r];
    }
  }
}

// ---------------- combine split-KV partials: O = (O0+O1)/(l0+l1) ----------------
__global__ __launch_bounds__(256) void combine(const float* __restrict__ Op0,
                                               const float* __restrict__ Op1,
                                               const float* __restrict__ Lp,
                                               u16* __restrict__ Ot) {
  int idx = blockIdx.x * 256 + threadIdx.x;  // [0, B*N*D) ; N*D = 1<<20
  int b = idx >> 20, rem = idx & ((1 << 20) - 1);
  int n = rem >> 9, ch = rem & 511, h = ch >> 6, dk = ch & 63;
  i64 o = ((i64)(b * HH + h) * NN + n) * 64 + dk;
  float l0 = Lp[(i64)(b * HH + h) * NN + n];
  float l1 = Lp[(i64)BB * HH * NN + (i64)(b * HH + h) * NN + n];
  Ot[(i64)(b * NN + n) * DD + ch] = f2bf((Op0[o] + Op1[o]) / (l0 + l1));
}

extern "C" void kernel_launch(void* const* d_in, const int* in_sizes, int n_in,
                              void* d_out, int out_size, void* d_ws, size_t ws_size,
                              hipStream_t stream) {
  (void)in_sizes; (void)n_in; (void)out_size; (void)ws_size;
  const float* iq    = (const float*)d_in[0];
  const float* kt    = (const float*)d_in[1];
  const float* vv    = (const float*)d_in[2];
  const int*   mask  = (const int*)d_in[3];
  const float* Wq    = (const float*)d_in[4];
  const float* bq    = (const float*)d_in[5];
  const float* Wk    = (const float*)d_in[6];
  const float* bk    = (const float*)d_in[7];
  const float* Wv    = (const float*)d_in[8];
  const float* bv    = (const float*)d_in[9];
  const float* Wm    = (const float*)d_in[10];
  const float* bm    = (const float*)d_in[11];
  const float* W1    = (const float*)d_in[12];
  const float* b1    = (const float*)d_in[13];
  const float* gamma_= (const float*)d_in[14];
  const float* beta_ = (const float*)d_in[15];
  const float* rmean = (const float*)d_in[16];
  const float* rvar  = (const float*)d_in[17];
  const float* W2    = (const float*)d_in[18];
  const float* b2    = (const float*)d_in[19];

  char* ws = (char*)d_ws;
  u16* cat = (u16*)(ws + OFF_CAT);
  u16* xkt = (u16*)(ws + OFF_XKT);
  u16* xvt = (u16*)(ws + OFF_XVT);
  u16* qh  = (u16*)(ws + OFF_QH);
  u16* kh  = (u16*)(ws + OFF_KH);
  u16* vt  = (u16*)(ws + OFF_VT);
  u16* ot  = (u16*)(ws + OFF_OT);
  u16* ht  = (u16*)(ws + OFF_HT);
  u16* wqp = (u16*)(ws + OFF_WQP);
  u16* wkp = (u16*)(ws + OFF_WKP);
  u16* wvp = (u16*)(ws + OFF_WVP);
  u16* wmp = (u16*)(ws + OFF_WMP);
  u16* w1b = (u16*)(ws + OFF_W1B);
  u16* w2b = (u16*)(ws + OFF_W2B);
  float* bqp = (float*)(ws + OFF_BQP);
  float* bkp = (float*)(ws + OFF_BKP);
  float* bvp = (float*)(ws + OFF_BVP);
  float* bna = (float*)(ws + OFF_BNA);
  float* bnc = (float*)(ws + OFF_BNC);
  u32* mw = (u32*)(ws + OFF_MSK);
  float* op0 = (float*)(ws + OFF_OP0);
  float* op1 = (float*)(ws + OFF_OP1);
  float* lp  = (float*)(ws + OFF_LP);

  prep_kernel<<<2817, 256, 0, stream>>>(Wq, Wk, Wv, Wm, W1, W2, bq, bk, bv, b1, gamma_, beta_,
                                        rmean, rvar, mask, wqp, wkp, wvp, wmp, w1b, w2b,
                                        bqp, bkp, bvp, bna, bnc, mw);
  transpose_cvt<<<dim3(64, 16, 6), 256, 0, stream>>>(iq, kt, vv, cat, xkt, xvt);

  // Q proj (scaled by QSC): C[n][o'] -> Qh[b][h][n][dk]
  GArgs qa{cat + DD, D2, (i64)NN * D2, wqp, DD, 0, qh, 0, (i64)HH * NN * DKc, bqp, nullptr, DD, QSC};
  gemm_bt<1><<<dim3(16, 8, 2), 256, 0, stream>>>(qa);
  // K proj
  GArgs ka{xkt, DD, (i64)NN * DD, wkp, DD, 0, kh, 0, (i64)HH * NN * DKc, bkp, nullptr, DD, 1.f};
  gemm_bt<1><<<dim3(16, 8, 2), 256, 0, stream>>>(ka);
  // V proj: C[o'][m] -> Vt[b][h][dk][m]
  GArgs va{wvp, DD, 0, xvt, DD, (i64)NN * DD, vt, NN, (i64)HH * DKc * NN, bvp, nullptr, DD, 1.f};
  gemm_bt<2><<<dim3(4, 32, 2), 256, 0, stream>>>(va);

  flash_attn<<<dim3(32, 8, 4), 256, 0, stream>>>(qh, kh, vt, (const u64*)mw, op0, op1, lp);
  combine<<<8192, 256, 0, stream>>>(op0, op1, lp, ot);

  // merge: C[n][o] -> catT[:, 0:512]
  GArgs ma{ot, DD, (i64)NN * DD, wmp, DD, 0, cat, D2, (i64)NN * D2, bm, nullptr, DD, 1.f};
  gemm_bt<0><<<dim3(16, 8, 2), 256, 0, stream>>>(ma);
  // W1 + BN + ReLU
  GArgs wa{cat, D2, (i64)NN * D2, w1b, D2, 0, ht, D2, (i64)NN * D2, bna, bnc, D2, 1.f};
  gemm_bt<3><<<dim3(16, 16, 2), 256, 0, stream>>>(wa);
  // W2 -> d_out (fp32)
  GArgs w2a{w2b, D2, 0, ht, D2, (i64)NN * D2, d_out, NN, (i64)DD * NN, b2, nullptr, D2, 1.f};
  gemm_bt<4><<<dim3(4, 32, 2), 256, 0, stream>>>(w2a);
}

// Round 3
// 233.470 us; speedup vs baseline: 1.3763x; 1.1221x over previous
//
#include <hip/hip_runtime.h>

typedef unsigned short u16;
typedef unsigned int u32;
typedef unsigned long long u64;
typedef long long i64;
typedef __bf16 bf16x8 __attribute__((ext_vector_type(8)));
typedef u16 u16x8 __attribute__((ext_vector_type(8)));
typedef u32 u32x2 __attribute__((ext_vector_type(2)));
typedef float f32x4 __attribute__((ext_vector_type(4)));

#define DEV __device__ __forceinline__

// problem constants (fixed by harness)
constexpr int BB = 2, DD = 512, NN = 2048, HH = 8, DKc = 64, D2 = 1024;

// Q pre-scale: 1/sqrt(64) * log2(e)  (folded into Q so softmax uses native exp2)
constexpr float QSC = 0.125f * 1.44269504088896340736f;

// workspace byte offsets (16B aligned)
constexpr i64 OFF_CAT = 0;              // bf16 [B][N][D2] concatT; [512:1024)=init_query^T
constexpr i64 OFF_XKT = 8388608;        // bf16 [B][N][D] key_t^T
constexpr i64 OFF_XVT = 12582912;       // bf16 [B][N][D] value^T
constexpr i64 OFF_QH  = 16777216;       // bf16 [B][H][N][DK] (Q pre-scaled by QSC)
constexpr i64 OFF_KH  = 20971520;       // bf16 [B][H][N][DK]
constexpr i64 OFF_VT  = 25165824;       // bf16 [B][H][DK][N] (m k'-permuted within 64-blocks)
constexpr i64 OFF_OT  = 29360128;       // bf16 [B][N][D]
constexpr i64 OFF_HT  = 33554432;       // bf16 [B][N][D2]
constexpr i64 OFF_WQP = 41943040;       // bf16 512x512 row-perm o'=h*64+dk
constexpr i64 OFF_WKP = 42467328;
constexpr i64 OFF_WVP = 42991616;
constexpr i64 OFF_WMP = 43515904;       // bf16 512x512 col-perm
constexpr i64 OFF_W1B = 44040192;       // bf16 1024x1024
constexpr i64 OFF_W2B = 46137344;       // bf16 512x1024
constexpr i64 OFF_BQP = 47185920;       // f32 512 (permuted)
constexpr i64 OFF_BKP = 47187968;
constexpr i64 OFF_BVP = 47190016;
constexpr i64 OFF_BNA = 47192064;       // f32 1024 BN scale
constexpr i64 OFF_BNC = 47196160;       // f32 1024 BN shift (incl b1)
constexpr i64 OFF_MSK = 47200256;       // bit-packed mask, 1 MB

DEV u16 f2bf(float f) {  // round-to-nearest-even f32->bf16
  u32 u = __float_as_uint(f);
  u = u + 0x7FFFu + ((u >> 16) & 1u);
  return (u16)(u >> 16);
}

// pack two f32 -> two bf16 (truncation) in ONE v_perm_b32
DEV u32 packbf(float lo, float hi) {
  return __builtin_amdgcn_perm(__float_as_uint(hi), __float_as_uint(lo), 0x07060302u);
}

DEV float fexp2(float x) {
#if __has_builtin(__builtin_amdgcn_exp2f)
  return __builtin_amdgcn_exp2f(x);
#else
  return exp2f(x);
#endif
}

DEV bf16x8 ldfrag(const u16* p) {  // 16B-aligned LDS fragment load
  bf16x8 v;
  __builtin_memcpy(&v, __builtin_assume_aligned(p, 16), 16);
  return v;
}

DEV bf16x8 ldfrag8(const u16* p) {  // 8B-aligned 16B LDS fragment load (2x b64)
  bf16x8 v;
  __builtin_memcpy(&v, __builtin_assume_aligned(p, 8), 16);
  return v;
}

DEV bf16x8 ones8() {  // bf16 1.0 x8
  u16x8 u = {0x3F80, 0x3F80, 0x3F80, 0x3F80, 0x3F80, 0x3F80, 0x3F80, 0x3F80};
  bf16x8 v;
  __builtin_memcpy(&v, &u, 16);
  return v;
}

// async global->LDS, 16B per lane; LDS dest = wave-uniform base + lane*16
DEV void gload16(const void* g, void* lds) {
  __builtin_amdgcn_global_load_lds((__attribute__((address_space(1))) void*)g,
                                   (__attribute__((address_space(3))) void*)lds, 16, 0, 0);
}

DEV f32x4 mfma16(bf16x8 a, bf16x8 b, f32x4 c) {
  return __builtin_amdgcn_mfma_f32_16x16x32_bf16(a, b, c, 0, 0, 0);
}

// ---------------- prep: weight convert/permute, BN fold, mask bit-pack ----------------
__global__ __launch_bounds__(256) void prep_kernel(
    const float* __restrict__ Wq, const float* __restrict__ Wk, const float* __restrict__ Wv,
    const float* __restrict__ Wm, const float* __restrict__ W1, const float* __restrict__ W2,
    const float* __restrict__ bq, const float* __restrict__ bk, const float* __restrict__ bv,
    const float* __restrict__ b1, const float* __restrict__ gamma_, const float* __restrict__ beta_,
    const float* __restrict__ rmean, const float* __restrict__ rvar, const int* __restrict__ mask,
    u16* __restrict__ wqp, u16* __restrict__ wkp, u16* __restrict__ wvp, u16* __restrict__ wmp,
    u16* __restrict__ w1b, u16* __restrict__ w2b,
    float* __restrict__ bqp, float* __restrict__ bkp, float* __restrict__ bvp,
    float* __restrict__ bna, float* __restrict__ bnc, u32* __restrict__ mw) {
  const int blk = blockIdx.x, t = threadIdx.x;
  if (blk < 768) {  // Wq/Wk/Wv row-permute: dst row o'=h*64+dk <- src row dk*8+h
    const int which = blk >> 8, lb = blk & 255;
    const float* W = which == 0 ? Wq : (which == 1 ? Wk : Wv);
    u16* dst = which == 0 ? wqp : (which == 1 ? wkp : wvp);
    for (int e = lb * 256 + t; e < 262144; e += 65536) {
      int op = e >> 9, i = e & 511;
      int dk = op & 63, h = op >> 6;
      dst[e] = f2bf(W[(dk * 8 + h) * 512 + i]);
    }
  } else if (blk < 1024) {  // Wm column-permute
    const int lb = blk - 768;
    for (int e = lb * 256 + t; e < 262144; e += 65536) {
      int o = e >> 9, c = e & 511;
      int dk = c & 63, h = c >> 6;
      wmp[e] = f2bf(Wm[o * 512 + dk * 8 + h]);
    }
  } else if (blk < 1536) {  // W1 convert
    const int lb = blk - 1024;
    for (int e = lb * 256 + t; e < 1048576; e += 131072) w1b[e] = f2bf(W1[e]);
  } else if (blk < 1792) {  // W2 convert
    const int lb = blk - 1536;
    for (int e = lb * 256 + t; e < 524288; e += 65536) w2b[e] = f2bf(W2[e]);
  } else if (blk == 1792) {  // vectors: permuted biases + folded BN
    for (int e = t; e < 512; e += 256) {
      int src = (e & 63) * 8 + (e >> 6);
      bqp[e] = bq[src]; bkp[e] = bk[src]; bvp[e] = bv[src];
    }
    for (int e = t; e < 1024; e += 256) {
      float a = gamma_[e] * rsqrtf(rvar[e] + 1e-5f);
      bna[e] = a;
      bnc[e] = (b1[e] - rmean[e]) * a + beta_[e];
    }
  } else {  // mask pack: each lane packs its own 32 consecutive ints -> one u32
    const int tid = (blk - 1793) * 256 + t;  // [0, 262144)
    const i64 base = (i64)tid * 32;
    const int4* mp = (const int4*)(mask + base);
    u32 word = 0;
#pragma unroll
    for (int j = 0; j < 8; ++j) {
      int4 x = mp[j];
      u32 nib = (x.x != 0 ? 1u : 0u) | (x.y != 0 ? 2u : 0u) | (x.z != 0 ? 4u : 0u) |
                (x.w != 0 ? 8u : 0u);
      word |= nib << (j * 4);
    }
    mw[tid] = word;
  }
}

// ---------------- transpose+convert: (B,D,N) f32 -> (B,N,D) bf16 ----------------
__global__ __launch_bounds__(256) void transpose_cvt(const float* __restrict__ iq,
                                                     const float* __restrict__ kt,
                                                     const float* __restrict__ vv,
                                                     u16* __restrict__ cat, u16* __restrict__ xkt,
                                                     u16* __restrict__ xvt) {
  __shared__ float tile[32][33];
  const int z = blockIdx.z, tensor = z >> 1, b = z & 1;
  const float* src = tensor == 0 ? iq : (tensor == 1 ? kt : vv);
  src += (i64)b * DD * NN;
  u16* dst; i64 ldd; int coff;
  if (tensor == 0)      { dst = cat + (i64)b * NN * D2; ldd = D2; coff = DD; }
  else if (tensor == 1) { dst = xkt + (i64)b * NN * DD; ldd = DD; coff = 0; }
  else                  { dst = xvt + (i64)b * NN * DD; ldd = DD; coff = 0; }
  const int x0 = blockIdx.x * 32, y0 = blockIdx.y * 32;
  const int col = threadIdx.x & 31, rg = threadIdx.x >> 5;
#pragma unroll
  for (int i = 0; i < 4; ++i) {
    int row = rg + i * 8;
    tile[row][col] = src[(i64)(y0 + row) * NN + x0 + col];
  }
  __syncthreads();
#pragma unroll
  for (int i = 0; i < 4; ++i) {
    int rr = rg + i * 8;
    dst[(i64)(x0 + rr) * ldd + coff + y0 + col] = f2bf(tile[col][rr]);
  }
}

// ---------------- shared GEMM core: BMxBN tile, BK=64, 4 waves 2x2 ----------------
// AM/AN = per-wave 16x16 tiles in m/n. BM=AM*32, BN=AN*32.
template <int AM, int AN>
DEV void gemm_core(const u16* __restrict__ A, i64 lda, const u16* __restrict__ Bp, i64 ldb,
                   int K, u16* As, u16* Bs, f32x4 (&acc)[AM][AN]) {
  constexpr int BM = AM * 32, BN = AN * 32;
  const int t = threadIdx.x, w = t >> 6, l = t & 63, quad = l >> 4, l15 = l & 15;
  const int wm = (w >> 1) * AM * 16, wn = (w & 1) * AN * 16;
  for (int kk = 0; kk < K; kk += 64) {
    __syncthreads();
#pragma unroll
    for (int j = 0; j < BM / 32; ++j) {
      int ch = j * 256 + w * 64 + l, r = ch >> 3, c = ch & 7;
      gload16(A + (i64)r * lda + kk + ((c ^ (r & 7)) << 3), As + (j * 256 + w * 64) * 8);
    }
#pragma unroll
    for (int j = 0; j < BN / 32; ++j) {
      int ch = j * 256 + w * 64 + l, r = ch >> 3, c = ch & 7;
      gload16(Bp + (i64)r * ldb + kk + ((c ^ (r & 7)) << 3), Bs + (j * 256 + w * 64) * 8);
    }
    __syncthreads();
#pragma unroll
    for (int kc = 0; kc < 2; ++kc) {
      const int sw = ((kc * 4 + quad) ^ (l15 & 7)) << 3;
      bf16x8 af[AM], bfr[AN];
#pragma unroll
      for (int i = 0; i < AM; ++i) af[i] = ldfrag(&As[(wm + i * 16 + l15) * 64 + sw]);
#pragma unroll
      for (int j = 0; j < AN; ++j) bfr[j] = ldfrag(&Bs[(wn + j * 16 + l15) * 64 + sw]);
#pragma unroll
      for (int i = 0; i < AM; ++i)
#pragma unroll
        for (int j = 0; j < AN; ++j) acc[i][j] = mfma16(af[i], bfr[j], acc[i][j]);
    }
  }
}

// ---------------- fused Q/K/V projection: z = op*2 + b ----------------
__global__ __launch_bounds__(256) void qkv_gemm(const u16* __restrict__ cat,
                                                const u16* __restrict__ xkt,
                                                const u16* __restrict__ xvt,
                                                const u16* __restrict__ wqp,
                                                const u16* __restrict__ wkp,
                                                const u16* __restrict__ wvp,
                                                const float* __restrict__ bqp,
                                                const float* __restrict__ bkp,
                                                const float* __restrict__ bvp,
                                                u16* __restrict__ qh, u16* __restrict__ kh,
                                                u16* __restrict__ vt) {
  __shared__ __align__(16) u16 As[128 * 64];
  __shared__ __align__(16) u16 Bs[64 * 64];
  const int z = blockIdx.z, op = z >> 1, b = z & 1;
  const int t = threadIdx.x, w = t >> 6, l = t & 63, quad = l >> 4, l15 = l & 15;
  const int wm = (w >> 1) * 64, wn = (w & 1) * 32;
  int mx, ny;
  const u16 *A, *Bp;
  i64 lda, ldb;
  if (op < 2) {  // Q/K: A = activations [2048][512], B = W [512][512]
    mx = blockIdx.x; ny = blockIdx.y;
    A = (op == 0 ? cat + DD : xkt);
    lda = (op == 0 ? D2 : DD);
    A += (i64)b * NN * lda + (i64)mx * 128 * lda;
    Bp = (op == 0 ? wqp : wkp) + (i64)ny * 64 * DD;
    ldb = DD;
  } else {  // V: A = Wv [512][512], B = value^T [2048][512]
    int f = blockIdx.x * 8 + blockIdx.y;
    mx = f >> 5; ny = f & 31;
    A = wvp + (i64)mx * 128 * DD; lda = DD;
    Bp = xvt + (i64)b * NN * DD + (i64)ny * 64 * DD; ldb = DD;
  }
  f32x4 acc[4][2] = {};
  gemm_core<4, 2>(A, lda, Bp, ldb, DD, As, Bs, acc);

  const int rowBase = mx * 128 + wm + quad * 4;
  const int colBase = ny * 64 + wn + l15;
  if (op < 2) {  // head scatter: col=h*64+dk -> [b][h][n][dk]; Q scaled by QSC
    const float* bias = (op == 0 ? bqp : bkp);
    const float sc = (op == 0 ? QSC : 1.f);
    u16* dst = (op == 0 ? qh : kh) + (i64)b * HH * NN * DKc;
#pragma unroll
    for (int j = 0; j < 2; ++j) {
      const int col = colBase + j * 16;
      const float cA = bias[col];
#pragma unroll
      for (int i = 0; i < 4; ++i)
#pragma unroll
        for (int r = 0; r < 4; ++r) {
          const int row = rowBase + i * 16 + r;
          dst[(i64)(col >> 6) * (NN * 64) + (i64)row * 64 + (col & 63)] =
              f2bf((acc[i][j][r] + cA) * sc);
        }
    }
  } else {  // V: row bias, store [b][o'][m'] with within-64 k'-permutation of m
    u16* dst = vt + (i64)b * HH * DKc * NN;
#pragma unroll
    for (int j = 0; j < 2; ++j) {
      const int col = colBase + j * 16;
      const int colp = (col & ~63) | (((col & 15) << 2) | ((col >> 4) & 3));
#pragma unroll
      for (int i = 0; i < 4; ++i)
#pragma unroll
        for (int r = 0; r < 4; ++r) {
          const int row = rowBase + i * 16 + r;
          dst[(i64)row * NN + colp] = f2bf(acc[i][j][r] + bvp[row]);
        }
    }
  }
}

// ---------------- generic gemm_bt: C[m][n] = A[m][:]·B[n][:] (+epilogue) ----------------
struct GArgs {
  const u16* A; i64 lda, sAb;
  const u16* B; i64 ldb, sBb;
  void* C; i64 ldc, sCb;
  const float* p1; const float* p2;
  int K;
};

template <int MODE, int AM, int AN>
__global__ __launch_bounds__(256) void gemm_bt(GArgs g) {
  __shared__ __align__(16) u16 As[AM * 32 * 64];
  __shared__ __align__(16) u16 Bs[AN * 32 * 64];
  const int t = threadIdx.x, w = t >> 6, l = t & 63, quad = l >> 4, l15 = l & 15;
  const int wm = (w >> 1) * AM * 16, wn = (w & 1) * AN * 16;
  const int bz = blockIdx.z;
  const u16* A = g.A + (i64)bz * g.sAb + (i64)blockIdx.x * (AM * 32) * g.lda;
  const u16* Bp = g.B + (i64)bz * g.sBb + (i64)blockIdx.y * (AN * 32) * g.ldb;
  f32x4 acc[AM][AN] = {};
  gemm_core<AM, AN>(A, g.lda, Bp, g.ldb, g.K, As, Bs, acc);

  const int rowBase = blockIdx.x * (AM * 32) + wm + quad * 4;
  const int colBase = blockIdx.y * (AN * 32) + wn + l15;
#pragma unroll
  for (int j = 0; j < AN; ++j) {
    const int col = colBase + j * 16;
    float cA = 0.f, cB = 0.f;
    if (MODE == 0) cA = g.p1[col];
    if (MODE == 3) { cA = g.p1[col]; cB = g.p2[col]; }
#pragma unroll
    for (int i = 0; i < AM; ++i) {
#pragma unroll
      for (int r = 0; r < 4; ++r) {
        const int row = rowBase + i * 16 + r;
        float v = acc[i][j][r];
        if (MODE == 0) {  // bf16, col bias (merge -> catT)
          ((u16*)g.C + (i64)bz * g.sCb)[(i64)row * g.ldc + col] = f2bf(v + cA);
        } else if (MODE == 3) {  // BN+ReLU
          float x = v * cA + cB;
          ((u16*)g.C + (i64)bz * g.sCb)[(i64)row * g.ldc + col] = f2bf(x > 0.f ? x : 0.f);
        } else {  // MODE 4: fp32 out, row bias (W2 -> d_out)
          ((float*)g.C + (i64)bz * g.sCb)[(i64)row * g.ldc + col] = v + g.p1[row];
        }
      }
    }
  }
}

// ---------------- flash attention v3: full-KV per block, packed P, ones-MFMA l ----------------
__global__ __launch_bounds__(256) void flash_attn(const u16* __restrict__ Qh,
                                                  const u16* __restrict__ Kh,
                                                  const u16* __restrict__ Vt,
                                                  const u64* __restrict__ MW,
                                                  u16* __restrict__ Ot) {
  __shared__ __align__(16) u16 Qs[64 * 64];
  __shared__ __align__(16) u16 Ks[64 * 64];
  __shared__ __align__(16) u16 Vs[64 * 64];
  __shared__ __align__(16) u16 Ps[4][16 * 68];  // per-wave [q=16][k'=64] pitch 68
  const int t = threadIdx.x, w = t >> 6, l = t & 63, quad = l >> 4, l15 = l & 15;
  const int nt = blockIdx.x, h = blockIdx.y, b = blockIdx.z;
  const u16* Qb = Qh + ((i64)(b * HH + h) * NN + nt * 64) * 64;
  const u16* Kb = Kh + (i64)(b * HH + h) * NN * 64;
  const u16* Vb = Vt + (i64)(b * HH + h) * 64 * NN;
  const bf16x8 ONE = ones8();
#pragma unroll
  for (int j = 0; j < 2; ++j) {  // stage Q (swizzled)
    int ch = j * 256 + w * 64 + l, r = ch >> 3, c = ch & 7;
    gload16(Qb + r * 64 + ((c ^ (r & 7)) << 3), &Qs[(j * 256 + w * 64) * 8]);
  }
  __syncthreads();
  bf16x8 qf[2];
#pragma unroll
  for (int kc = 0; kc < 2; ++kc)
    qf[kc] = ldfrag(&Qs[(w * 16 + l15) * 64 + (((kc * 4 + quad) ^ (l15 & 7)) << 3)]);

  f32x4 oacc[4] = {};
  f32x4 lacc = {};
  for (int mt = 0; mt < NN / 64; ++mt) {
    __syncthreads();
#pragma unroll
    for (int j = 0; j < 2; ++j) {  // stage K,V (swizzled)
      int ch = j * 256 + w * 64 + l, r = ch >> 3, c = ch & 7;
      gload16(Kb + (i64)mt * 4096 + r * 64 + ((c ^ (r & 7)) << 3), &Ks[(j * 256 + w * 64) * 8]);
      gload16(Vb + (i64)r * NN + mt * 64 + ((c ^ (r & 7)) << 3), &Vs[(j * 256 + w * 64) * 8]);
    }
    __syncthreads();
    // S' = Q K^T : 16 rows x 64 cols per wave (Q pre-scaled)
    f32x4 s[4];
#pragma unroll
    for (int ct = 0; ct < 4; ++ct) {
      const int sw = l15 & 7;
      bf16x8 k0 = ldfrag(&Ks[(ct * 16 + l15) * 64 + ((quad ^ sw) << 3)]);
      bf16x8 k1 = ldfrag(&Ks[(ct * 16 + l15) * 64 + (((4 + quad) ^ sw) << 3)]);
      f32x4 z = {};
      z = mfma16(qf[0], k0, z);
      z = mfma16(qf[1], k1, z);
      s[ct] = z;
    }
    // p = exp2(s'), masked via AND on packed bf16 pairs; k' = l15*4 + ct layout
#pragma unroll
    for (int r = 0; r < 4; ++r) {
      int n = nt * 64 + w * 16 + quad * 4 + r;
      u64 sh = MW[(i64)(b * NN + n) * 32 + mt] >> l15;
      u32 m01 = ((u32)sh & 0x00010001u) * 0xFFFFu;
      u32 m23 = ((u32)(sh >> 32) & 0x00010001u) * 0xFFFFu;
      u32 w0 = packbf(fexp2(s[0][r]), fexp2(s[1][r])) & m01;
      u32 w1 = packbf(fexp2(s[2][r]), fexp2(s[3][r])) & m23;
      u32x2 pair = {w0, w1};
      __builtin_memcpy(__builtin_assume_aligned(&Ps[w][(quad * 4 + r) * 68 + l15 * 4], 8), &pair, 8);
    }
    asm volatile("" ::: "memory");
    bf16x8 pf0 = ldfrag8(&Ps[w][l15 * 68 + quad * 8]);
    bf16x8 pf1 = ldfrag8(&Ps[w][l15 * 68 + 32 + quad * 8]);
    lacc = mfma16(pf0, ONE, lacc);  // row-sums via ones-column
    lacc = mfma16(pf1, ONE, lacc);
#pragma unroll
    for (int dt = 0; dt < 4; ++dt) {
      const int sw = l15 & 7;
      bf16x8 v0 = ldfrag(&Vs[(dt * 16 + l15) * 64 + ((quad ^ sw) << 3)]);
      bf16x8 v1 = ldfrag(&Vs[(dt * 16 + l15) * 64 + (((4 + quad) ^ sw) << 3)]);
      oacc[dt] = mfma16(pf0, v0, oacc[dt]);
      oacc[dt] = mfma16(pf1, v1, oacc[dt]);
    }
  }
  // epilogue: normalize and store O[n][dk] -> Ot[b][n][h*64+dk]
  float inv[4];
#pragma unroll
  for (int r = 0; r < 4; ++r) inv[r] = __builtin_amdgcn_rcpf(lacc[r]);
#pragma unroll
  for (int dt = 0; dt < 4; ++dt)
#pragma unroll
    for (int r = 0; r < 4; ++r) {
      int n = nt * 64 + w * 16 + quad * 4 + r;
      Ot[((i64)b * NN + n) * DD + h * DKc + dt * 16 + l15] = f2bf(oacc[dt][r] * inv[r]);
    }
}

extern "C" void kernel_launch(void* const* d_in, const int* in_sizes, int n_in,
                              void* d_out, int out_size, void* d_ws, size_t ws_size,
                              hipStream_t stream) {
  (void)in_sizes; (void)n_in; (void)out_size; (void)ws_size;
  const float* iq    = (const float*)d_in[0];
  const float* kt    = (const float*)d_in[1];
  const float* vv    = (const float*)d_in[2];
  const int*   mask  = (const int*)d_in[3];
  const float* Wq    = (const float*)d_in[4];
  const float* bq    = (const float*)d_in[5];
  const float* Wk    = (const float*)d_in[6];
  const float* bk    = (const float*)d_in[7];
  const float* Wv    = (const float*)d_in[8];
  const float* bv    = (const float*)d_in[9];
  const float* Wm    = (const float*)d_in[10];
  const float* bm    = (const float*)d_in[11];
  const float* W1    = (const float*)d_in[12];
  const float* b1    = (const float*)d_in[13];
  const float* gamma_= (const float*)d_in[14];
  const float* beta_ = (const float*)d_in[15];
  const float* rmean = (const float*)d_in[16];
  const float* rvar  = (const float*)d_in[17];
  const float* W2    = (const float*)d_in[18];
  const float* b2    = (const float*)d_in[19];

  char* ws = (char*)d_ws;
  u16* cat = (u16*)(ws + OFF_CAT);
  u16* xkt = (u16*)(ws + OFF_XKT);
  u16* xvt = (u16*)(ws + OFF_XVT);
  u16* qh  = (u16*)(ws + OFF_QH);
  u16* kh  = (u16*)(ws + OFF_KH);
  u16* vt  = (u16*)(ws + OFF_VT);
  u16* ot  = (u16*)(ws + OFF_OT);
  u16* ht  = (u16*)(ws + OFF_HT);
  u16* wqp = (u16*)(ws + OFF_WQP);
  u16* wkp = (u16*)(ws + OFF_WKP);
  u16* wvp = (u16*)(ws + OFF_WVP);
  u16* wmp = (u16*)(ws + OFF_WMP);
  u16* w1b = (u16*)(ws + OFF_W1B);
  u16* w2b = (u16*)(ws + OFF_W2B);
  float* bqp = (float*)(ws + OFF_BQP);
  float* bkp = (float*)(ws + OFF_BKP);
  float* bvp = (float*)(ws + OFF_BVP);
  float* bna = (float*)(ws + OFF_BNA);
  float* bnc = (float*)(ws + OFF_BNC);
  u32* mw = (u32*)(ws + OFF_MSK);

  prep_kernel<<<2817, 256, 0, stream>>>(Wq, Wk, Wv, Wm, W1, W2, bq, bk, bv, b1, gamma_, beta_,
                                        rmean, rvar, mask, wqp, wkp, wvp, wmp, w1b, w2b,
                                        bqp, bkp, bvp, bna, bnc, mw);
  transpose_cvt<<<dim3(64, 16, 6), 256, 0, stream>>>(iq, kt, vv, cat, xkt, xvt);

  // fused Q/K/V projections: 768 blocks = 3/CU
  qkv_gemm<<<dim3(16, 8, 6), 256, 0, stream>>>(cat, xkt, xvt, wqp, wkp, wvp, bqp, bkp, bvp,
                                               qh, kh, vt);

  flash_attn<<<dim3(32, 8, 2), 256, 0, stream>>>(qh, kh, vt, (const u64*)mw, ot);

  // merge: C[n][o] -> catT[:, 0:512]  (64x64 tiles, 512 blocks)
  GArgs ma{ot, DD, (i64)NN * DD, wmp, DD, 0, cat, D2, (i64)NN * D2, bm, nullptr, DD};
  gemm_bt<0, 2, 2><<<dim3(32, 8, 2), 256, 0, stream>>>(ma);
  // W1 + BN + ReLU  (128x64 tiles, 512 blocks)
  GArgs wa{cat, D2, (i64)NN * D2, w1b, D2, 0, ht, D2, (i64)NN * D2, bna, bnc, D2};
  gemm_bt<3, 4, 2><<<dim3(16, 16, 2), 256, 0, stream>>>(wa);
  // W2 -> d_out (fp32)  (64x64 tiles, 512 blocks)
  GArgs w2a{w2b, D2, 0, ht, D2, (i64)NN * D2, d_out, NN, (i64)DD * NN, b2, nullptr, D2};
  gemm_bt<4, 2, 2><<<dim3(8, 32, 2), 256, 0, stream>>>(w2a);
}